// Round 10
// baseline (449.391 us; speedup 1.0000x reference)
//
#include <hip/hip_runtime.h>
#include <hip/hip_fp16.h>
#include <math.h>

#define NN 50000
#define NE 1600000
#define KORD 5
#define NB 196          // ceil(NN/256)
#define QTR 12500       // node quarter (k_deg)
#define GE 782          // epi grid: ceil(NN/64)
#define MT 64           // epi node tile
#define NBK 1563        // ceil(NN/32) destination buckets (32 nodes each)
#define NBP 1600        // padded bucket stride
#define NCH 128         // chunks for bucket kernels
#define ECH (NE / NCH)  // 12500
#define EC4 (NE / 64)   // 25000 (k_deg chunks)

#define SCALE_W 2097152.0f          // 2^21 spmm fixed point
#define INV_SCALE_W (1.0f / 2097152.0f)
#define SCALE_D 4194304.0f          // 2^22 degree fixed point
#define INV_SCALE_D (1.0f / 4194304.0f)

// ---------------- deg: LDS int-fixed-point weighted row histogram ----------
__global__ __launch_bounds__(1024) void k_deg(const int* __restrict__ ei,
                                              const float* __restrict__ ew,
                                              int* __restrict__ deg_g) {
    __shared__ int h[QTR];   // 50 KB
    int q = blockIdx.x >> 6, ch = blockIdx.x & 63;
    for (int i = threadIdx.x; i < QTR; i += 1024) h[i] = 0;
    __syncthreads();
    int base = ch * EC4, lo = q * QTR;
    for (int e = base + threadIdx.x; e < base + EC4; e += 1024) {
        int li = ei[e] - lo;
        if ((unsigned)li < (unsigned)QTR)
            atomicAdd(&h[li], __float2int_rn(ew[e] * SCALE_D));  // ds_add_u32
    }
    __syncthreads();
    int* outp = deg_g + blockIdx.x * QTR;
    for (int i = threadIdx.x; i < QTR; i += 1024) outp[i] = h[i];
}

__global__ __launch_bounds__(256) void k_dis2(const int* __restrict__ deg_g,
                                              float* __restrict__ dis) {
    int n = blockIdx.x * 256 + threadIdx.x;
    if (n >= NN) return;
    int q = n / QTR, i = n % QTR;
    const int* p = deg_g + (q * 64) * QTR + i;
    int s = 0;
#pragma unroll
    for (int c = 0; c < 64; c++) s += p[c * QTR];
    float d = (float)s * INV_SCALE_D;
    dis[n] = s > 0 ? rsqrtf(fmaxf(d, 1e-30f)) : 0.f;
}

// ---------------- bucket histogram: bh[ch][b] ----------
__global__ __launch_bounds__(1024) void k_bhist(const int* __restrict__ ei,
                                                int* __restrict__ bh) {
    __shared__ int hist[NBK];
    int ch = blockIdx.x;
    for (int i = threadIdx.x; i < NBK; i += 1024) hist[i] = 0;
    __syncthreads();
    const int* cols = ei + NE;
    int base = ch * ECH;
    for (int e = base + threadIdx.x; e < base + ECH; e += 1024)
        atomicAdd(&hist[cols[e] >> 5], 1);
    __syncthreads();
    int* outp = bh + ch * NBP;
    for (int b = threadIdx.x; b < NBK; b += 1024) outp[b] = hist[b];
}

// bucket totals across chunks (zero-pads to NBP for the pair-scan)
__global__ __launch_bounds__(256) void k_btot(const int* __restrict__ bh,
                                              int* __restrict__ tot) {
    int b = blockIdx.x * 256 + threadIdx.x;
    if (b >= NBP) return;
    int s = 0;
    if (b < NBK) {
#pragma unroll 8
        for (int ch = 0; ch < NCH; ch++) s += bh[ch * NBP + b];
    }
    tot[b] = s;
}

// one block: pair-compressed exclusive scan of 1563 totals -> off_bk
__global__ __launch_bounds__(1024) void k_bscan1(const int* __restrict__ tot,
                                                 int* __restrict__ off_bk) {
    __shared__ int s[1024];
    int t = threadIdx.x;
    int a0 = (2 * t < NBP) ? tot[2 * t] : 0;
    int a1 = (2 * t + 1 < NBP) ? tot[2 * t + 1] : 0;
    s[t] = a0 + a1;
    __syncthreads();
    for (int d = 1; d < 1024; d <<= 1) {
        int u = (t >= d) ? s[t - d] : 0;
        __syncthreads();
        s[t] += u;
        __syncthreads();
    }
    int excl = (t == 0) ? 0 : s[t - 1];
    if (2 * t < NBK) off_bk[2 * t] = excl;
    if (2 * t + 1 < NBK) off_bk[2 * t + 1] = excl + a0;
    if (t == 0) off_bk[NBK] = NE;
}

// per-(chunk,bucket) absolute cursors written back into bh
__global__ __launch_bounds__(256) void k_bcur(int* __restrict__ bh,
                                              const int* __restrict__ off_bk) {
    int b = blockIdx.x * 256 + threadIdx.x;
    if (b >= NBK) return;
    int run = off_bk[b];
    for (int ch = 0; ch < NCH; ch++) {
        int v = bh[ch * NBP + b];
        bh[ch * NBP + b] = run;
        run += v;
    }
}

// coarse permute: record = (r | local_c<<16, weight-bits)
__global__ __launch_bounds__(1024) void k_cperm(const int* __restrict__ ei,
                                                const float* __restrict__ ew,
                                                const float* __restrict__ dis,
                                                const int* __restrict__ bh,
                                                int2* __restrict__ edges) {
    __shared__ int cur[NBK];
    int ch = blockIdx.x;
    const int* cp = bh + ch * NBP;
    for (int b = threadIdx.x; b < NBK; b += 1024) cur[b] = cp[b];
    __syncthreads();
    int base = ch * ECH;
    for (int e = base + threadIdx.x; e < base + ECH; e += 1024) {
        int r = ei[e], c = ei[NE + e];
        float w = -dis[r] * ew[e] * dis[c];
        int pos = atomicAdd(&cur[c >> 5], 1);   // ds_add_u32, native
        int packed = (int)((unsigned)r | ((unsigned)(c & 31) << 16));
        edges[pos] = make_int2(packed, __float_as_int(w));
    }
}

// ---------------- per-bucket exact counting sort by local dest ----------
__global__ __launch_bounds__(256) void k_sort(const int* __restrict__ off_bk,
                                              const int2* __restrict__ edges,
                                              int2* __restrict__ edges2) {
    __shared__ int cnt[32];
    __shared__ int cur[32];
    int b = blockIdx.x;
    int e0 = off_bk[b], e1 = off_bk[b + 1];
    if (threadIdx.x < 32) cnt[threadIdx.x] = 0;
    __syncthreads();
    for (int i = e0 + threadIdx.x; i < e1; i += 256)
        atomicAdd(&cnt[edges[i].x >> 16], 1);
    __syncthreads();
    if (threadIdx.x == 0) {
        int run = e0;
#pragma unroll
        for (int k = 0; k < 32; k++) { cur[k] = run; run += cnt[k]; }
    }
    __syncthreads();
    for (int i = e0 + threadIdx.x; i < e1; i += 256) {
        int2 e = edges[i];
        int p = atomicAdd(&cur[e.x >> 16], 1);
        edges2[p] = e;
    }
}

// ---------------- spmm: sorted strips, batch-4 fold (4 gather chains) -------
#define SPMM_FLUSH(CC)                                         \
    {                                                          \
        int* A = &acc[CC][sub * 4];                            \
        atomicAdd(A + 0, __float2int_rn(ax * SCALE_W));        \
        atomicAdd(A + 1, __float2int_rn(ay * SCALE_W));        \
        atomicAdd(A + 2, __float2int_rn(az * SCALE_W));        \
        atomicAdd(A + 3, __float2int_rn(aw * SCALE_W));        \
        ax = 0.f; ay = 0.f; az = 0.f; aw = 0.f;                \
    }

__global__ __launch_bounds__(256) void k_spmm(const int* __restrict__ off_bk,
                                              const int2* __restrict__ edges,
                                              const float* __restrict__ vin,
                                              const float* __restrict__ prev,
                                              float* __restrict__ vout,
                                              float scale) {
    __shared__ int acc[32][33];
    int b = blockIdx.x;
    for (int i = threadIdx.x; i < 32 * 33; i += 256) (&acc[0][0])[i] = 0;
    __syncthreads();
    int e0 = off_bk[b], e1 = off_bk[b + 1];
    int len = e1 - e0;
    int g = threadIdx.x >> 3, sub = threadIdx.x & 7;
    int S = (len + 31) >> 5;
    int i = e0 + g * S;
    int iE = i + S; if (iE > e1) iE = e1;
    const float4* vin4 = (const float4*)vin;
    if (i < iE) {
        int curc = edges[i].x >> 16;
        float ax = 0.f, ay = 0.f, az = 0.f, aw = 0.f;
        for (; i + 4 <= iE; i += 4) {
            int2 ea = edges[i];
            int2 eb = edges[i + 1];
            int2 ec = edges[i + 2];
            int2 ed = edges[i + 3];
            float4 va = vin4[(ea.x & 0xffff) * 8 + sub];   // 4 independent
            float4 vb = vin4[(eb.x & 0xffff) * 8 + sub];   // gather chains
            float4 vc = vin4[(ec.x & 0xffff) * 8 + sub];
            float4 vd = vin4[(ed.x & 0xffff) * 8 + sub];
            int c;
            float w;
            c = ea.x >> 16; if (c != curc) { SPMM_FLUSH(curc); curc = c; }
            w = __int_as_float(ea.y);
            ax = fmaf(w, va.x, ax); ay = fmaf(w, va.y, ay);
            az = fmaf(w, va.z, az); aw = fmaf(w, va.w, aw);
            c = eb.x >> 16; if (c != curc) { SPMM_FLUSH(curc); curc = c; }
            w = __int_as_float(eb.y);
            ax = fmaf(w, vb.x, ax); ay = fmaf(w, vb.y, ay);
            az = fmaf(w, vb.z, az); aw = fmaf(w, vb.w, aw);
            c = ec.x >> 16; if (c != curc) { SPMM_FLUSH(curc); curc = c; }
            w = __int_as_float(ec.y);
            ax = fmaf(w, vc.x, ax); ay = fmaf(w, vc.y, ay);
            az = fmaf(w, vc.z, az); aw = fmaf(w, vc.w, aw);
            c = ed.x >> 16; if (c != curc) { SPMM_FLUSH(curc); curc = c; }
            w = __int_as_float(ed.y);
            ax = fmaf(w, vd.x, ax); ay = fmaf(w, vd.y, ay);
            az = fmaf(w, vd.z, az); aw = fmaf(w, vd.w, aw);
        }
        for (; i < iE; i++) {
            int2 e = edges[i];
            float4 v = vin4[(e.x & 0xffff) * 8 + sub];
            int c = e.x >> 16;
            if (c != curc) { SPMM_FLUSH(curc); curc = c; }
            float w = __int_as_float(e.y);
            ax = fmaf(w, v.x, ax); ay = fmaf(w, v.y, ay);
            az = fmaf(w, v.z, az); aw = fmaf(w, v.w, aw);
        }
        SPMM_FLUSH(curc);
    }
    __syncthreads();
    float sf = scale * INV_SCALE_W;
    int base = b << 5;
    int nl = threadIdx.x >> 3, s4 = threadIdx.x & 7;
    int n = base + nl;
    if (n < NN) {
        const int* a = &acc[nl][s4 * 4];
        float4 o;
        if (prev) {
            float4 p = ((const float4*)prev)[n * 8 + s4];
            o = make_float4(fmaf(sf, (float)a[0], -p.x),
                            fmaf(sf, (float)a[1], -p.y),
                            fmaf(sf, (float)a[2], -p.z),
                            fmaf(sf, (float)a[3], -p.w));
        } else {
            o = make_float4(sf * (float)a[0], sf * (float)a[1],
                            sf * (float)a[2], sf * (float)a[3]);
        }
        ((float4*)vout)[n * 8 + s4] = o;
    }
}

// ---------------- epi1: fp16-staged LDS GEMM (K=160 -> 32z+32h) + GRU -------
// T in fp16 (23 KB) -> 6 blocks/CU. thread = (nq in 16, oq in 16):
// 4 nodes (stride 16) x 2 z-cols + 2 h-cols. Weights stay fp32.
__global__ __launch_bounds__(256) void k_epi1(
    const float* __restrict__ x, const float* __restrict__ t1,
    const float* __restrict__ t2, const float* __restrict__ t3,
    const float* __restrict__ t4, const float* __restrict__ Wx1,
    const float* __restrict__ bx1, const float* __restrict__ bh1,
    float* __restrict__ h) {
    __shared__ __half T[5][MT][36];  // stride 36 halfs: conflict-free, 4B-aligned
    int n0 = blockIdx.x * MT;
    const float* bufs[5] = {x, t1, t2, t3, t4};
#pragma unroll
    for (int b = 0; b < 5; b++) {
        for (int idx = threadIdx.x; idx < MT * 8; idx += 256) {
            int r = idx >> 3, c4 = idx & 7;
            int rr = n0 + r; if (rr >= NN) rr = NN - 1;
            float4 v = *(const float4*)(bufs[b] + rr * 32 + c4 * 4);
            __half2* dst = (__half2*)&T[b][r][c4 * 4];
            dst[0] = __floats2half2_rn(v.x, v.y);
            dst[1] = __floats2half2_rn(v.z, v.w);
        }
    }
    __syncthreads();
    int nq = threadIdx.x & 15, oq = threadIdx.x >> 4;
    int ob = oq * 2;
    const float* Wz = Wx1;
    const float* Wh = Wx1 + 2 * KORD * 32 * 32;
    float az_[4][2] = {{0.f}}, ah_[4][2] = {{0.f}};
#pragma unroll
    for (int b = 0; b < 5; b++) {
#pragma unroll 4
        for (int i = 0; i < 32; i++) {
            int kw = b * 1024 + i * 32 + ob;
            float wz0 = Wz[kw], wz1 = Wz[kw + 1];
            float wh0 = Wh[kw], wh1 = Wh[kw + 1];
#pragma unroll
            for (int a = 0; a < 4; a++) {
                float tx = __half2float(T[b][nq + 16 * a][i]);
                az_[a][0] = fmaf(tx, wz0, az_[a][0]);
                az_[a][1] = fmaf(tx, wz1, az_[a][1]);
                ah_[a][0] = fmaf(tx, wh0, ah_[a][0]);
                ah_[a][1] = fmaf(tx, wh1, ah_[a][1]);
            }
        }
    }
#pragma unroll
    for (int a = 0; a < 4; a++) {
        int n = n0 + nq + 16 * a;
        if (n < NN) {
#pragma unroll
            for (int c = 0; c < 2; c++) {
                int j = ob + c;
                float zz = az_[a][c] + bx1[j] + bh1[j];
                float hh = ah_[a][c] + bx1[64 + j] + bh1[64 + j];
                float z = 1.f / (1.f + __expf(-zz));
                float tt = __expf(-2.f * fabsf(hh));
                float ht = copysignf((1.f - tt) / (1.f + tt), hh);
                h[n * 32 + j] = fmaxf((1.f - z) * ht, 0.f);
            }
        }
    }
}

// ---------------- epi2: fp16-staged LDS GEMM + final linear ----------------
__global__ __launch_bounds__(256) void k_epi2(
    const float* __restrict__ hin, const float* __restrict__ t1,
    const float* __restrict__ t2, const float* __restrict__ t3,
    const float* __restrict__ t4, const float* __restrict__ Wx2,
    const float* __restrict__ bx2, const float* __restrict__ bh2,
    const float* __restrict__ Wl, const float* __restrict__ bl,
    float* __restrict__ out) {
    __shared__ __half T[5][MT][36];
    __shared__ float H2[MT][17];
    int n0 = blockIdx.x * MT;
    const float* bufs[5] = {hin, t1, t2, t3, t4};
#pragma unroll
    for (int b = 0; b < 5; b++) {
        for (int idx = threadIdx.x; idx < MT * 8; idx += 256) {
            int r = idx >> 3, c4 = idx & 7;
            int rr = n0 + r; if (rr >= NN) rr = NN - 1;
            float4 v = *(const float4*)(bufs[b] + rr * 32 + c4 * 4);
            __half2* dst = (__half2*)&T[b][r][c4 * 4];
            dst[0] = __floats2half2_rn(v.x, v.y);
            dst[1] = __floats2half2_rn(v.z, v.w);
        }
    }
    __syncthreads();
    int nq = threadIdx.x & 15, j = threadIdx.x >> 4;
    const float* Wz = Wx2;
    const float* Wh = Wx2 + 2 * KORD * 32 * 16;
    float az_[4] = {0.f}, ah_[4] = {0.f};
#pragma unroll
    for (int b = 0; b < 5; b++) {
#pragma unroll 4
        for (int i = 0; i < 32; i++) {
            int kw = b * 512 + i * 16 + j;
            float wz0 = Wz[kw], wh0 = Wh[kw];
#pragma unroll
            for (int a = 0; a < 4; a++) {
                float tx = __half2float(T[b][nq + 16 * a][i]);
                az_[a] = fmaf(tx, wz0, az_[a]);
                ah_[a] = fmaf(tx, wh0, ah_[a]);
            }
        }
    }
#pragma unroll
    for (int a = 0; a < 4; a++) {
        float zz = az_[a] + bx2[j] + bh2[j];
        float hh = ah_[a] + bx2[32 + j] + bh2[32 + j];
        float z = 1.f / (1.f + __expf(-zz));
        float tt = __expf(-2.f * fabsf(hh));
        float ht = copysignf((1.f - tt) / (1.f + tt), hh);
        H2[nq + 16 * a][j] = fmaxf((1.f - z) * ht, 0.f);
    }
    __syncthreads();
    for (int idx = threadIdx.x; idx < MT * 12; idx += 256) {
        int n = idx / 12, p = idx % 12;
        int gn = n0 + n;
        if (gn < NN) {
            float o = bl[p];
#pragma unroll
            for (int jj = 0; jj < 16; jj++) o = fmaf(H2[n][jj], Wl[p * 16 + jj], o);
            out[gn * 12 + p] = o;
        }
    }
}

// ---------------- launch ----------------

extern "C" void kernel_launch(void* const* d_in, const int* in_sizes, int n_in,
                              void* d_out, int out_size, void* d_ws, size_t ws_size,
                              hipStream_t stream) {
    const float* x   = (const float*)d_in[0];
    const int*   ei  = (const int*)d_in[1];
    const float* ew  = (const float*)d_in[2];
    const float* Wx1 = (const float*)d_in[3];
    const float* bx1 = (const float*)d_in[4];
    const float* bh1 = (const float*)d_in[6];
    const float* Wx2 = (const float*)d_in[7];
    const float* bx2 = (const float*)d_in[8];
    const float* bh2 = (const float*)d_in[10];
    const float* Wl  = (const float*)d_in[11];
    const float* bl  = (const float*)d_in[12];
    float* out = (float*)d_out;

    float* ws     = (float*)d_ws;
    float* dis    = ws;                         // 50048 floats
    int*   bh     = (int*)(ws + 50048);         // NCH*NBP ints
    int*   tot    = bh + NCH * NBP;             // NBP ints
    int*   off_bk = tot + NBP;                  // NBP ints
    int2*  edges  = (int2*)(off_bk + NBP);      // NE int2 (coarse)
    int2*  edges2 = edges + NE;                 // NE int2 (exact-sorted)
    float* T1     = (float*)(edges2 + NE);      // NN*32 floats each
    float* T2     = T1 + NN * 32;
    float* T3     = T2 + NN * 32;
    float* T4     = T3 + NN * 32;
    float* hb     = T4 + NN * 32;
    int*   deg_g  = (int*)T1;  // 256*QTR ints (T1+T2 region, dead before spmm)

    k_deg  <<<256, 1024, 0, stream>>>(ei, ew, deg_g);
    k_dis2 <<<NB, 256, 0, stream>>>(deg_g, dis);
    k_bhist<<<NCH, 1024, 0, stream>>>(ei, bh);
    k_btot <<<7, 256, 0, stream>>>(bh, tot);
    k_bscan1<<<1, 1024, 0, stream>>>(tot, off_bk);
    k_bcur <<<7, 256, 0, stream>>>(bh, off_bk);
    k_cperm<<<NCH, 1024, 0, stream>>>(ei, ew, dis, bh, edges);
    k_sort <<<NBK, 256, 0, stream>>>(off_bk, edges, edges2);

    // ---- cell 1: v = x ----
    k_spmm<<<NBK, 256, 0, stream>>>(off_bk, edges2, x,  nullptr, T1, 1.f);
    k_spmm<<<NBK, 256, 0, stream>>>(off_bk, edges2, T1, x,       T2, 2.f);
    k_spmm<<<NBK, 256, 0, stream>>>(off_bk, edges2, T2, T1,      T3, 2.f);
    k_spmm<<<NBK, 256, 0, stream>>>(off_bk, edges2, T3, T2,      T4, 2.f);
    k_epi1<<<GE, 256, 0, stream>>>(x, T1, T2, T3, T4, Wx1, bx1, bh1, hb);

    // ---- cell 2: v = hb ----
    k_spmm<<<NBK, 256, 0, stream>>>(off_bk, edges2, hb, nullptr, T1, 1.f);
    k_spmm<<<NBK, 256, 0, stream>>>(off_bk, edges2, T1, hb,      T2, 2.f);
    k_spmm<<<NBK, 256, 0, stream>>>(off_bk, edges2, T2, T1,      T3, 2.f);
    k_spmm<<<NBK, 256, 0, stream>>>(off_bk, edges2, T3, T2,      T4, 2.f);
    k_epi2<<<GE, 256, 0, stream>>>(hb, T1, T2, T3, T4, Wx2, bx2, bh2, Wl, bl, out);
}